// Round 4
// baseline (126.871 us; speedup 1.0000x reference)
//
#include <hip/hip_runtime.h>
#include <hip/hip_bf16.h>
#include <math.h>

// SelfRetentionV1: B=2,H=16,L=2048,DK=128,DV=128
// out[b,l,h,d] = RMSNorm_d( (QK^T * gamma^(i-j) / max(1,|rowsum|)) @ V )
#define B_ 2
#define H_ 16
#define L_ 2048
#define DK_ 128
#define DV_ 128
#define QBLK 64
#define KVBLK 64
#define NIT (L_/QBLK)   // 32

typedef __bf16 bf16x8 __attribute__((ext_vector_type(8)));
typedef float  f32x4  __attribute__((ext_vector_type(4)));

static __device__ __forceinline__ unsigned short f2bf(float f) {
    union { float f; unsigned int u; } x; x.f = f;
    unsigned int r = x.u + 0x7fffu + ((x.u >> 16) & 1u);  // RNE
    return (unsigned short)(r >> 16);
}

// async global->LDS, 16B per lane; LDS dest = wave-uniform base + lane*16
static __device__ __forceinline__ void gload_lds16(const void* g, void* l) {
    __builtin_amdgcn_global_load_lds(
        (const __attribute__((address_space(1))) unsigned int*)g,
        (__attribute__((address_space(3))) unsigned int*)l,
        16, 0, 0);
}

// K tile rows are 256B: swizzle bits 4-6 by row&7 (involution, row bits >=8)
#define KSWZ(d) ((d) ^ ((((d) >> 8) & 7) << 4))
// V tile rows are 128B: row bits >=7
#define VSWZ(d) ((d) ^ ((((d) >> 7) & 7) << 4))

// ---- pre-kernel 1: fp32 -> bf16 flat convert (K) ----
__global__ void cvt_bf16_kernel(const float* __restrict__ in,
                                unsigned short* __restrict__ out, int n4) {
    int i = blockIdx.x * blockDim.x + threadIdx.x;
    int stride = gridDim.x * blockDim.x;
    for (; i < n4; i += stride) {
        float4 f = ((const float4*)in)[i];
        uint2 o;
        o.x = (unsigned)f2bf(f.x) | ((unsigned)f2bf(f.y) << 16);
        o.y = (unsigned)f2bf(f.z) | ((unsigned)f2bf(f.w) << 16);
        ((uint2*)out)[i] = o;
    }
}

// ---- pre-kernel 2: V[bh][l][dv] -> VT[bh][dv][l], bf16 ----
__global__ void transpose_v_kernel(const float* __restrict__ v,
                                   unsigned short* __restrict__ vt) {
    __shared__ unsigned short lds[64][130];   // +2 pad: col reads conflict-free
    int blk = blockIdx.x;
    int ltile = blk & (L_/64 - 1);
    int bh = blk / (L_/64);
    const float* vp = v + ((size_t)bh * L_ + (size_t)ltile * 64) * DV_;
    unsigned short* vo = vt + (size_t)bh * DV_ * L_ + ltile * 64;
    int t = threadIdx.x;
    int r0 = t >> 5, c0 = (t & 31) * 4;
    #pragma unroll
    for (int it = 0; it < 8; ++it) {
        int row = r0 + 8 * it;
        float4 f = *(const float4*)(vp + row * DV_ + c0);
        lds[row][c0 + 0] = f2bf(f.x);
        lds[row][c0 + 1] = f2bf(f.y);
        lds[row][c0 + 2] = f2bf(f.z);
        lds[row][c0 + 3] = f2bf(f.w);
    }
    __syncthreads();
    int dvb = t >> 3, seg = t & 7;
    #pragma unroll
    for (int ot = 0; ot < 4; ++ot) {
        int dv = dvb + 32 * ot;
        unsigned short a0 = lds[seg*8+0][dv], a1 = lds[seg*8+1][dv];
        unsigned short a2 = lds[seg*8+2][dv], a3 = lds[seg*8+3][dv];
        unsigned short a4 = lds[seg*8+4][dv], a5 = lds[seg*8+5][dv];
        unsigned short a6 = lds[seg*8+6][dv], a7 = lds[seg*8+7][dv];
        uint4 st;
        st.x = (unsigned)a0 | ((unsigned)a1 << 16);
        st.y = (unsigned)a2 | ((unsigned)a3 << 16);
        st.z = (unsigned)a4 | ((unsigned)a5 << 16);
        st.w = (unsigned)a6 | ((unsigned)a7 << 16);
        *(uint4*)(vo + (size_t)dv * L_ + seg * 8) = st;
    }
}

// ---- main kernel: 2 waves x 32 Q-rows (2x FLOP per LDS byte vs 4x16) ----
__launch_bounds__(128, 1)
__global__ void retention_kernel(const float* __restrict__ q,
                                 const unsigned short* __restrict__ kb,
                                 const unsigned short* __restrict__ vt_,
                                 float* __restrict__ out) {
    // K tile [64][128] bf16 (16KB), V^T tile [128][64] bf16 (16KB), x2 dbuf
    __shared__ __align__(16) unsigned short kbuf[2][64 * 128];
    __shared__ __align__(16) unsigned short vbuf[2][128 * 64];
    __shared__ __align__(16) unsigned short p_lds[2][32][72];  // wave-private

    // bh->XCD-pinned remap (xcd = bid%8): 4 bh per XCD -> ~4MB K+V ~= L2
    int bid = blockIdx.x;
    int x    = bid & 7;          // XCD id
    int t_   = bid >> 3;
    int slot = t_ & 31;
    int hi   = t_ >> 5;          // 0..3
    int itile = (hi & 1) ? (31 - slot) : slot;
    int bh = hi * 8 + x;
    int b = bh >> 4, h = bh & 15;

    int tid = threadIdx.x;
    int lane = tid & 63;
    int w = tid >> 6;                   // 0..1
    int g = lane >> 4;                  // 0..3
    int c = lane & 15;                  // 0..15

    int i_wave = itile * QBLK + w * 32;

    const unsigned short* kbp = kb  + (size_t)bh * L_ * DK_;
    const unsigned short* vtp = vt_ + (size_t)bh * DV_ * L_;

    // ---- stage tile 0 first (DMA runs under the setup below) ----
    {
        const char* ksrc = (const char*)kbp;          // rows 0..63
        const char* vsrc = (const char*)vtp;          // j offset 0
        char* kdst = (char*)&kbuf[0][0];
        char* vdst = (char*)&vbuf[0][0];
        #pragma unroll
        for (int is = 0; is < 8; ++is) {
            int dw = is * 2048 + w * 1024;            // wave-uniform dest
            int d  = dw + lane * 16;
            gload_lds16(ksrc + KSWZ(d), kdst + dw);
            int sv = VSWZ(d);
            gload_lds16(vsrc + (size_t)(sv >> 7) * (L_ * 2) + (sv & 127), vdst + dw);
        }
    }

    float ex = exp2f((float)(-5 - h));
    float gamma = 1.0f - ex;
    float log2g = log1pf(-ex) * 1.44269504088896f;   // accurate near gamma~1

    // column decay factors: gamma^-(16*nt + c)   (max gamma^-63 ~ 7.4, safe)
    float bcol[4];
    bcol[0] = exp2f(log2g * (float)(-c));
    float g16i = exp2f(log2g * (-16.0f));
    bcol[1] = bcol[0] * g16i; bcol[2] = bcol[1] * g16i; bcol[3] = bcol[2] * g16i;

    // row decay: gamma^(i - j_base), i = i_wave + m*16 + g*4 + r
    float arow0 = exp2f(log2g * (float)(i_wave + g * 4));  // m=0,r=0 base
    float g16 = exp2f(log2g * 16.0f);                      // gamma^16 (m step)
    float gm64i = exp2f(log2g * (-64.0f));                 // per-jt advance

    // hoist Q fragments: qf[m][ks], rows i_wave + m*16 + c
    bf16x8 qf[2][4];
    #pragma unroll
    for (int m = 0; m < 2; ++m) {
        const float* qp = q + ((size_t)bh * L_ + (i_wave + m * 16 + c)) * DK_ + g * 8;
        #pragma unroll
        for (int ks = 0; ks < 4; ++ks) {
            float4 f0 = *(const float4*)(qp + ks * 32);
            float4 f1 = *(const float4*)(qp + ks * 32 + 4);
            union { bf16x8 v; unsigned short u[8]; } A;
            A.u[0]=f2bf(f0.x); A.u[1]=f2bf(f0.y); A.u[2]=f2bf(f0.z); A.u[3]=f2bf(f0.w);
            A.u[4]=f2bf(f1.x); A.u[5]=f2bf(f1.y); A.u[6]=f2bf(f1.z); A.u[7]=f2bf(f1.w);
            qf[m][ks] = A.v;
        }
    }

    f32x4 o[2][8];
    f32x4 zero = {0.f, 0.f, 0.f, 0.f};
    #pragma unroll
    for (int m = 0; m < 2; ++m)
        #pragma unroll
        for (int nt = 0; nt < 8; ++nt) o[m][nt] = zero;
    float rowsum[2][4] = {{0.f,0.f,0.f,0.f},{0.f,0.f,0.f,0.f}};

    int swz = (c & 7) << 4;   // read-side XOR (row&7 == c&7 for rows nt*16+c)

    __syncthreads();          // implicit vmcnt(0) drain: buf0 resident
    int cur = 0;

    for (int jt = 0; jt <= itile; ++jt) {
        // ---- issue next tile's stage (lands during compute below) ----
        if (jt < itile) {
            int jb = (jt + 1) * KVBLK;
            const char* ksrc = (const char*)(kbp + (size_t)jb * DK_);
            const char* vsrc = (const char*)(vtp + jb);
            char* kdst = (char*)&kbuf[cur ^ 1][0];
            char* vdst = (char*)&vbuf[cur ^ 1][0];
            #pragma unroll
            for (int is = 0; is < 8; ++is) {
                int dw = is * 2048 + w * 1024;
                int d  = dw + lane * 16;
                gload_lds16(ksrc + KSWZ(d), kdst + dw);
                int sv = VSWZ(d);
                gload_lds16(vsrc + (size_t)(sv >> 7) * (L_ * 2) + (sv & 127), vdst + dw);
            }
        }

        const char* kb_c = (const char*)&kbuf[cur][0];
        const char* vb_c = (const char*)&vbuf[cur][0];

        float arow_m0 = arow0;
        arow0 *= gm64i;   // advance to next jt

        #pragma unroll
        for (int m = 0; m < 2; ++m) {
            // ---- S = Q K^T (16x64) from swizzled LDS; K-frags shared via L0/regs
            f32x4 s[4];
            #pragma unroll
            for (int nt = 0; nt < 4; ++nt) s[nt] = zero;
            #pragma unroll
            for (int ks = 0; ks < 4; ++ks) {
                #pragma unroll
                for (int nt = 0; nt < 4; ++nt) {
                    int krow = nt * 16 + c;
                    bf16x8 bfrag = *(const bf16x8*)(kb_c + krow * 256 + ((ks * 64 + g * 16) ^ swz));
                    s[nt] = __builtin_amdgcn_mfma_f32_16x16x32_bf16(qf[m][ks], bfrag, s[nt], 0, 0, 0);
                }
            }

            float arow[4];
            arow[0] = (m == 0) ? arow_m0 : arow_m0 * g16;
            arow[1] = arow[0] * gamma; arow[2] = arow[1] * gamma; arow[3] = arow[2] * gamma;

            if (jt == itile) {   // diagonal tile: per-element causal mask
                #pragma unroll
                for (int nt = 0; nt < 4; ++nt) {
                    int j = jt * KVBLK + nt * 16 + c;
                    #pragma unroll
                    for (int r = 0; r < 4; ++r) {
                        int i = i_wave + m * 16 + g * 4 + r;
                        float wgt = (j <= i) ? arow[r] * bcol[nt] : 0.0f;
                        float val = s[nt][r] * wgt;
                        rowsum[m][r] += val;
                        p_lds[w][m * 16 + g * 4 + r][nt * 16 + c] = f2bf(val);
                    }
                }
            } else {             // strictly-lower tile: no mask needed
                #pragma unroll
                for (int nt = 0; nt < 4; ++nt) {
                    #pragma unroll
                    for (int r = 0; r < 4; ++r) {
                        float val = s[nt][r] * (arow[r] * bcol[nt]);
                        rowsum[m][r] += val;
                        p_lds[w][m * 16 + g * 4 + r][nt * 16 + c] = f2bf(val);
                    }
                }
            }
        }
        // wave-private p_lds: per-wave in-order DS + compiler may-alias ordering

        // ---- O += P V from swizzled LDS V^T; V-frags reused across m ----
        #pragma unroll
        for (int ks = 0; ks < 2; ++ks) {
            bf16x8 pa0 = *(const bf16x8*)&p_lds[w][c][ks * 32 + g * 8];
            bf16x8 pa1 = *(const bf16x8*)&p_lds[w][16 + c][ks * 32 + g * 8];
            #pragma unroll
            for (int nt = 0; nt < 8; ++nt) {
                int vrow = nt * 16 + c;
                bf16x8 vb = *(const bf16x8*)(vb_c + vrow * 128 + ((ks * 64 + g * 16) ^ swz));
                o[0][nt] = __builtin_amdgcn_mfma_f32_16x16x32_bf16(pa0, vb, o[0][nt], 0, 0, 0);
                o[1][nt] = __builtin_amdgcn_mfma_f32_16x16x32_bf16(pa1, vb, o[1][nt], 0, 0, 0);
            }
        }

        // one barrier per tile: drains the stage issued above (had full compute
        // to land) and protects buf[cur^1] reads before next iter's overwrite
        __syncthreads();
        cur ^= 1;
    }

    // ---- epilogue: denom + RMSNorm (reductions within 16-lane groups) ----
    #pragma unroll
    for (int m = 0; m < 2; ++m) {
        float rs[4];
        #pragma unroll
        for (int r = 0; r < 4; ++r) {
            float vsum = rowsum[m][r];
            vsum += __shfl_xor(vsum, 1);
            vsum += __shfl_xor(vsum, 2);
            vsum += __shfl_xor(vsum, 4);
            vsum += __shfl_xor(vsum, 8);
            rs[r] = 1.0f / fmaxf(1.0f, fabsf(vsum));
        }
        #pragma unroll
        for (int nt = 0; nt < 8; ++nt)
            #pragma unroll
            for (int r = 0; r < 4; ++r) o[m][nt][r] *= rs[r];
        float scale[4];
        #pragma unroll
        for (int r = 0; r < 4; ++r) {
            float ss = 0.f;
            #pragma unroll
            for (int nt = 0; nt < 8; ++nt) ss += o[m][nt][r] * o[m][nt][r];
            ss += __shfl_xor(ss, 1);
            ss += __shfl_xor(ss, 2);
            ss += __shfl_xor(ss, 4);
            ss += __shfl_xor(ss, 8);
            scale[r] = rsqrtf(ss * (1.0f / 128.0f) + 1e-6f);
        }
        #pragma unroll
        for (int r = 0; r < 4; ++r) {
            int i = i_wave + m * 16 + g * 4 + r;
            float* op = out + (((size_t)b * L_ + i) * H_ + h) * DV_ + c;
            #pragma unroll
            for (int nt = 0; nt < 8; ++nt) op[nt * 16] = o[m][nt][r] * scale[r];
        }
    }
}

// ---- fp32 fixup for row i=0 (single-term row: eps-magnified bf16 error) ----
__global__ void fix_row0_kernel(const float* __restrict__ q,
                                const float* __restrict__ k,
                                const float* __restrict__ v,
                                float* __restrict__ out) {
    int bh = blockIdx.x;            // 0..31
    int lane = threadIdx.x;         // 0..63
    const float* qp = q + (size_t)bh * L_ * DK_;
    const float* kp = k + (size_t)bh * L_ * DK_;
    const float* vp = v + (size_t)bh * L_ * DV_;
    float part = qp[lane] * kp[lane] + qp[lane + 64] * kp[lane + 64];
    #pragma unroll
    for (int mm = 1; mm < 64; mm <<= 1) part += __shfl_xor(part, mm);
    float r00 = part;
    float cf = r00 / fmaxf(1.0f, fabsf(r00));
    float o0 = cf * vp[lane], o1 = cf * vp[lane + 64];
    float ss = o0 * o0 + o1 * o1;
    #pragma unroll
    for (int mm = 1; mm < 64; mm <<= 1) ss += __shfl_xor(ss, mm);
    float sc = rsqrtf(ss * (1.0f / 128.0f) + 1e-6f);
    int b = bh >> 4, h = bh & 15;
    float* op = out + ((size_t)b * L_ * H_ + h) * DV_;   // i = 0
    op[lane] = o0 * sc;
    op[lane + 64] = o1 * sc;
}

extern "C" void kernel_launch(void* const* d_in, const int* in_sizes, int n_in,
                              void* d_out, int out_size, void* d_ws, size_t ws_size,
                              hipStream_t stream) {
    const float* q = (const float*)d_in[0];
    const float* k = (const float*)d_in[1];
    const float* v = (const float*)d_in[2];
    // d_in[3] decay_mask (256MB) and d_in[4] intra_decay are recomputed on the fly
    float* out = (float*)d_out;

    unsigned short* kb = (unsigned short*)d_ws;                 // 16 MB
    unsigned short* vt = kb + (size_t)B_ * H_ * L_ * DK_;       // 16 MB

    int n4 = B_ * H_ * L_ * DK_ / 4;
    cvt_bf16_kernel<<<2048, 256, 0, stream>>>(k, kb, n4);
    transpose_v_kernel<<<B_ * H_ * (L_ / 64), 256, 0, stream>>>(v, vt);
    retention_kernel<<<B_ * H_ * NIT, 128, 0, stream>>>(q, kb, vt, out);
    fix_row0_kernel<<<B_ * H_, 64, 0, stream>>>(q, k, v, out);
}

// Round 5
// 111.446 us; speedup vs baseline: 1.1384x; 1.1384x over previous
//
#include <hip/hip_runtime.h>
#include <hip/hip_bf16.h>
#include <math.h>

// SelfRetentionV1: B=2,H=16,L=2048,DK=128,DV=128
// out[b,l,h,d] = RMSNorm_d( (QK^T * gamma^(i-j) / max(1,|rowsum|)) @ V )
#define B_ 2
#define H_ 16
#define L_ 2048
#define DK_ 128
#define DV_ 128
#define QBLK 64
#define KVBLK 64
#define NIT (L_/QBLK)   // 32

typedef __bf16 bf16x8 __attribute__((ext_vector_type(8)));
typedef float  f32x16 __attribute__((ext_vector_type(16)));

static __device__ __forceinline__ unsigned short f2bf(float f) {
    union { float f; unsigned int u; } x; x.f = f;
    unsigned int r = x.u + 0x7fffu + ((x.u >> 16) & 1u);  // RNE
    return (unsigned short)(r >> 16);
}

// async global->LDS, 16B per lane; LDS dest = wave-uniform base + lane*16
static __device__ __forceinline__ void gload_lds16(const void* g, void* l) {
    __builtin_amdgcn_global_load_lds(
        (const __attribute__((address_space(1))) unsigned int*)g,
        (__attribute__((address_space(3))) unsigned int*)l,
        16, 0, 0);
}

// K tile rows are 256B: swizzle bits 4-6 by row&7 (involution, row bits >=8)
#define KSWZ(d) ((d) ^ ((((d) >> 8) & 7) << 4))
// V tile rows are 128B: row bits >=7
#define VSWZ(d) ((d) ^ ((((d) >> 7) & 7) << 4))

// ---- pre-kernel 1: fp32 -> bf16 flat convert (K) ----
__global__ void cvt_bf16_kernel(const float* __restrict__ in,
                                unsigned short* __restrict__ out, int n4) {
    int i = blockIdx.x * blockDim.x + threadIdx.x;
    int stride = gridDim.x * blockDim.x;
    for (; i < n4; i += stride) {
        float4 f = ((const float4*)in)[i];
        uint2 o;
        o.x = (unsigned)f2bf(f.x) | ((unsigned)f2bf(f.y) << 16);
        o.y = (unsigned)f2bf(f.z) | ((unsigned)f2bf(f.w) << 16);
        ((uint2*)out)[i] = o;
    }
}

// ---- pre-kernel 2: V[bh][l][dv] -> VT[bh][dv][l], bf16 ----
__global__ void transpose_v_kernel(const float* __restrict__ v,
                                   unsigned short* __restrict__ vt) {
    __shared__ unsigned short lds[64][130];   // +2 pad: col reads conflict-free
    int blk = blockIdx.x;
    int ltile = blk & (L_/64 - 1);
    int bh = blk / (L_/64);
    const float* vp = v + ((size_t)bh * L_ + (size_t)ltile * 64) * DV_;
    unsigned short* vo = vt + (size_t)bh * DV_ * L_ + ltile * 64;
    int t = threadIdx.x;
    int r0 = t >> 5, c0 = (t & 31) * 4;
    #pragma unroll
    for (int it = 0; it < 8; ++it) {
        int row = r0 + 8 * it;
        float4 f = *(const float4*)(vp + row * DV_ + c0);
        lds[row][c0 + 0] = f2bf(f.x);
        lds[row][c0 + 1] = f2bf(f.y);
        lds[row][c0 + 2] = f2bf(f.z);
        lds[row][c0 + 3] = f2bf(f.w);
    }
    __syncthreads();
    int dvb = t >> 3, seg = t & 7;
    #pragma unroll
    for (int ot = 0; ot < 4; ++ot) {
        int dv = dvb + 32 * ot;
        unsigned short a0 = lds[seg*8+0][dv], a1 = lds[seg*8+1][dv];
        unsigned short a2 = lds[seg*8+2][dv], a3 = lds[seg*8+3][dv];
        unsigned short a4 = lds[seg*8+4][dv], a5 = lds[seg*8+5][dv];
        unsigned short a6 = lds[seg*8+6][dv], a7 = lds[seg*8+7][dv];
        uint4 st;
        st.x = (unsigned)a0 | ((unsigned)a1 << 16);
        st.y = (unsigned)a2 | ((unsigned)a3 << 16);
        st.z = (unsigned)a4 | ((unsigned)a5 << 16);
        st.w = (unsigned)a6 | ((unsigned)a7 << 16);
        *(uint4*)(vo + (size_t)dv * L_ + seg * 8) = st;
    }
}

// ---- main kernel: 4 waves, quadrant split (rh,kh), 32x32x16 MFMA ----
// wave (rh,kh): q-rows rh*32..+31, kv-cols kh*32..+31 of each 64x64 tile.
// 32x32 frags double FLOP/LDS-byte; occupancy stays 2 waves/SIMD (vs r4 bug).
__launch_bounds__(256, 2)
__global__ void retention_kernel(const float* __restrict__ q,
                                 const unsigned short* __restrict__ kb,
                                 const unsigned short* __restrict__ vt_,
                                 float* __restrict__ out) {
    __shared__ __align__(16) unsigned short kbuf[2][64 * 128];  // 32 KB dbuf
    __shared__ __align__(16) unsigned short vbuf[2][128 * 64];  // 32 KB dbuf
    // P stage, wave-private: 32 rows x 64B data in 128B stride (XOR headroom)
    __shared__ __align__(16) unsigned short p_lds[4][32][64];   // 16 KB

    // bh->XCD-pinned remap (xcd = bid%8): 4 bh per XCD -> ~4MB K+V ~= L2
    int bid = blockIdx.x;
    int x    = bid & 7;          // XCD id
    int t_   = bid >> 3;
    int slot = t_ & 31;
    int hi   = t_ >> 5;          // 0..3
    int itile = (hi & 1) ? (31 - slot) : slot;
    int bh = hi * 8 + x;
    int b = bh >> 4, h = bh & 15;

    int tid = threadIdx.x;
    int lane = tid & 63;
    int w = tid >> 6;                   // 0..3
    int rh = w >> 1;                    // q-row half
    int kh = w & 1;                     // kv half
    int jl = lane & 31;
    int hl = lane >> 5;

    int i_base = itile * QBLK + rh * 32;

    const unsigned short* kbp = kb  + (size_t)bh * L_ * DK_;
    const unsigned short* vtp = vt_ + (size_t)bh * DV_ * L_;

    // ---- stage tile 0 (DMA runs under the setup below) ----
    {
        const char* ksrc = (const char*)kbp;
        const char* vsrc = (const char*)vtp;
        char* kdst = (char*)&kbuf[0][0];
        char* vdst = (char*)&vbuf[0][0];
        #pragma unroll
        for (int is = 0; is < 4; ++is) {
            int dw = is * 4096 + w * 1024;            // wave-uniform dest
            int d  = dw + lane * 16;
            gload_lds16(ksrc + KSWZ(d), kdst + dw);
            int sv = VSWZ(d);
            gload_lds16(vsrc + (size_t)(sv >> 7) * (L_ * 2) + (sv & 127), vdst + dw);
        }
    }

    float ex = exp2f((float)(-5 - h));
    float gamma = 1.0f - ex;
    float log2g = log1pf(-ex) * 1.44269504088896f;   // accurate near gamma~1

    // weight(i,j) = gamma^(i-j) = arow_base * wfac[reg]  (+ causal mask on diag)
    // arow_base = gamma^(i_base + 4*hl - j_base); wfac = gamma^rowpat_s * colfac
    int jrel = kh * 32 + jl;                         // j - j_base
    float colfac = exp2f(log2g * (float)(-jrel));    // gamma^-(jrel), <= 7.4
    float g2 = gamma * gamma;
    float gp1[4] = {1.0f, gamma, g2, g2 * gamma};
    float g8 = exp2f(log2g * 8.0f);
    float g8_2 = g8 * g8;
    float gp8[4] = {1.0f, g8, g8_2, g8_2 * g8};
    float wfac[16];
    #pragma unroll
    for (int reg = 0; reg < 16; ++reg)
        wfac[reg] = gp1[reg & 3] * gp8[reg >> 2] * colfac;
    float arow_base = exp2f(log2g * (float)(i_base + 4 * hl));   // j_base=0
    float gm64i = exp2f(log2g * (-64.0f));
    int icmp = rh * 32 + 4 * hl - jrel;   // mask: icmp + rowpat_s >= 0

    // Q A-frags: row = i_base + jl, k = ks*16 + hl*8 + 0..7
    bf16x8 qf[8];
    {
        const float* qp = q + ((size_t)bh * L_ + (i_base + jl)) * DK_ + hl * 8;
        #pragma unroll
        for (int ks = 0; ks < 8; ++ks) {
            float4 f0 = *(const float4*)(qp + ks * 16);
            float4 f1 = *(const float4*)(qp + ks * 16 + 4);
            union { bf16x8 v; unsigned short u[8]; } A;
            A.u[0]=f2bf(f0.x); A.u[1]=f2bf(f0.y); A.u[2]=f2bf(f0.z); A.u[3]=f2bf(f0.w);
            A.u[4]=f2bf(f1.x); A.u[5]=f2bf(f1.y); A.u[6]=f2bf(f1.z); A.u[7]=f2bf(f1.w);
            qf[ks] = A.v;
        }
    }

    f32x16 o[4];
    #pragma unroll
    for (int nt = 0; nt < 4; ++nt)
        #pragma unroll
        for (int e = 0; e < 16; ++e) o[nt][e] = 0.0f;
    float rowsum[16];
    #pragma unroll
    for (int reg = 0; reg < 16; ++reg) rowsum[reg] = 0.0f;

    char* pwb = (char*)&p_lds[w][0][0];
    int rswz = (jl & 7) << 4;   // read-side XOR for K/V (row&7 == jl&7)

    __syncthreads();            // implicit vmcnt(0): buf0 resident
    int cur = 0;

    for (int jt = 0; jt <= itile; ++jt) {
        if (jt < itile) {       // issue next tile's stage (lands during compute)
            int jb = (jt + 1) * KVBLK;
            const char* ksrc = (const char*)(kbp + (size_t)jb * DK_);
            const char* vsrc = (const char*)(vtp + jb);
            char* kdst = (char*)&kbuf[cur ^ 1][0];
            char* vdst = (char*)&vbuf[cur ^ 1][0];
            #pragma unroll
            for (int is = 0; is < 4; ++is) {
                int dw = is * 4096 + w * 1024;
                int d  = dw + lane * 16;
                gload_lds16(ksrc + KSWZ(d), kdst + dw);
                int sv = VSWZ(d);
                gload_lds16(vsrc + (size_t)(sv >> 7) * (L_ * 2) + (sv & 127), vdst + dw);
            }
        }

        const char* kb_c = (const char*)&kbuf[cur][0];
        const char* vb_c = (const char*)&vbuf[cur][0];

        // ---- S = Q K^T (32x32): B-frag = K[kh*32+jl][ks*16 + hl*8 ..] ----
        f32x16 s;
        #pragma unroll
        for (int e = 0; e < 16; ++e) s[e] = 0.0f;
        #pragma unroll
        for (int ks = 0; ks < 8; ++ks) {
            bf16x8 bfrag = *(const bf16x8*)(kb_c + (kh * 32 + jl) * 256
                                            + ((ks * 32 + hl * 16) ^ rswz));
            s = __builtin_amdgcn_mfma_f32_32x32x16_bf16(qf[ks], bfrag, s, 0, 0, 0);
        }

        float ab = arow_base;
        arow_base *= gm64i;     // advance to next jt

        // ---- decay + (diag) mask + rowsum + P write (C-layout -> A-layout) ----
        if (jt == itile) {
            #pragma unroll
            for (int reg = 0; reg < 16; ++reg) {
                int rps = (reg & 3) + 8 * (reg >> 2);        // static part
                float val = (icmp + rps >= 0) ? s[reg] * (ab * wfac[reg]) : 0.0f;
                rowsum[reg] += val;
                int rp = rps + 4 * hl;
                *(unsigned short*)(pwb + rp * 128 + ((2 * jl) ^ ((rp & 7) << 4))) = f2bf(val);
            }
        } else {
            #pragma unroll
            for (int reg = 0; reg < 16; ++reg) {
                int rps = (reg & 3) + 8 * (reg >> 2);
                float val = s[reg] * (ab * wfac[reg]);
                rowsum[reg] += val;
                int rp = rps + 4 * hl;
                *(unsigned short*)(pwb + rp * 128 + ((2 * jl) ^ ((rp & 7) << 4))) = f2bf(val);
            }
        }
        // wave-private p_lds: per-wave in-order DS keeps write->read correct

        // ---- O += P V : A = P[jl][ks2*16+hl*8..], B = V^T frags ----
        #pragma unroll
        for (int ks2 = 0; ks2 < 2; ++ks2) {
            bf16x8 pa = *(const bf16x8*)(pwb + jl * 128
                                         + ((ks2 * 32 + hl * 16) ^ rswz));
            #pragma unroll
            for (int nt = 0; nt < 4; ++nt) {
                bf16x8 vb = *(const bf16x8*)(vb_c + (nt * 32 + jl) * 128
                                             + ((kh * 64 + ks2 * 32 + hl * 16) ^ rswz));
                o[nt] = __builtin_amdgcn_mfma_f32_32x32x16_bf16(pa, vb, o[nt], 0, 0, 0);
            }
        }

        __syncthreads();        // drains stage (had full compute to land)
        cur ^= 1;
    }

    // ---- in-wave rowsum reduce over this wave's 32 j (lanes & 31) ----
    #pragma unroll
    for (int reg = 0; reg < 16; ++reg) {
        float v = rowsum[reg];
        v += __shfl_xor(v, 1);
        v += __shfl_xor(v, 2);
        v += __shfl_xor(v, 4);
        v += __shfl_xor(v, 8);
        v += __shfl_xor(v, 16);
        rowsum[reg] = v;
    }

    // ---- cross-wave (kv-half) reduction via LDS, then normalize + store ----
    float* exch = (float*)&kbuf[0][0];      // pair rh at +rh*4096 floats (16KB)
    float* rsx  = (float*)&vbuf[0][0];      // pair rh at +rh*32 floats
    if (kh == 1) {
        float* eb = exch + rh * 4096;
        #pragma unroll
        for (int nt = 0; nt < 4; ++nt)
            #pragma unroll
            for (int qg = 0; qg < 4; ++qg) {
                float4 vv = { o[nt][4*qg], o[nt][4*qg+1], o[nt][4*qg+2], o[nt][4*qg+3] };
                *(float4*)(eb + ((nt * 32 + jl) * 32) + 8 * qg + 4 * hl) = vv;
            }
        if (jl == 0) {
            float* rb = rsx + rh * 32;
            #pragma unroll
            for (int reg = 0; reg < 16; ++reg)
                rb[(reg & 3) + 8 * (reg >> 2) + 4 * hl] = rowsum[reg];
        }
    }
    __syncthreads();
    if (kh == 0) {
        float* eb = exch + rh * 4096;
        float* rb = rsx + rh * 32;
        #pragma unroll
        for (int nt = 0; nt < 4; ++nt)
            #pragma unroll
            for (int qg = 0; qg < 4; ++qg) {
                float4 pv = *(const float4*)(eb + ((nt * 32 + jl) * 32) + 8 * qg + 4 * hl);
                o[nt][4*qg]   += pv.x;
                o[nt][4*qg+1] += pv.y;
                o[nt][4*qg+2] += pv.z;
                o[nt][4*qg+3] += pv.w;
            }
        float dn[16], scale[16];
        #pragma unroll
        for (int reg = 0; reg < 16; ++reg) {
            float tot = rowsum[reg] + rb[(reg & 3) + 8 * (reg >> 2) + 4 * hl];
            dn[reg] = 1.0f / fmaxf(1.0f, fabsf(tot));
        }
        #pragma unroll
        for (int nt = 0; nt < 4; ++nt)
            #pragma unroll
            for (int reg = 0; reg < 16; ++reg) o[nt][reg] *= dn[reg];
        #pragma unroll
        for (int reg = 0; reg < 16; ++reg) {
            float ss = 0.0f;
            #pragma unroll
            for (int nt = 0; nt < 4; ++nt) ss += o[nt][reg] * o[nt][reg];
            ss += __shfl_xor(ss, 1);
            ss += __shfl_xor(ss, 2);
            ss += __shfl_xor(ss, 4);
            ss += __shfl_xor(ss, 8);
            ss += __shfl_xor(ss, 16);
            scale[reg] = rsqrtf(ss * (1.0f / 128.0f) + 1e-6f);
        }
        #pragma unroll
        for (int reg = 0; reg < 16; ++reg) {
            int i_abs = i_base + (reg & 3) + 8 * (reg >> 2) + 4 * hl;
            float* op = out + (((size_t)b * L_ + i_abs) * H_ + h) * DV_ + jl;
            #pragma unroll
            for (int nt = 0; nt < 4; ++nt)
                op[nt * 32] = o[nt][reg] * scale[reg];
        }
    }
}

// ---- fp32 fixup for row i=0 (single-term row: eps-magnified bf16 error) ----
__global__ void fix_row0_kernel(const float* __restrict__ q,
                                const float* __restrict__ k,
                                const float* __restrict__ v,
                                float* __restrict__ out) {
    int bh = blockIdx.x;            // 0..31
    int lane = threadIdx.x;         // 0..63
    const float* qp = q + (size_t)bh * L_ * DK_;
    const float* kp = k + (size_t)bh * L_ * DK_;
    const float* vp = v + (size_t)bh * L_ * DV_;
    float part = qp[lane] * kp[lane] + qp[lane + 64] * kp[lane + 64];
    #pragma unroll
    for (int mm = 1; mm < 64; mm <<= 1) part += __shfl_xor(part, mm);
    float r00 = part;
    float cf = r00 / fmaxf(1.0f, fabsf(r00));
    float o0 = cf * vp[lane], o1 = cf * vp[lane + 64];
    float ss = o0 * o0 + o1 * o1;
    #pragma unroll
    for (int mm = 1; mm < 64; mm <<= 1) ss += __shfl_xor(ss, mm);
    float sc = rsqrtf(ss * (1.0f / 128.0f) + 1e-6f);
    int b = bh >> 4, h = bh & 15;
    float* op = out + ((size_t)b * L_ * H_ + h) * DV_;   // i = 0
    op[lane] = o0 * sc;
    op[lane + 64] = o1 * sc;
}

extern "C" void kernel_launch(void* const* d_in, const int* in_sizes, int n_in,
                              void* d_out, int out_size, void* d_ws, size_t ws_size,
                              hipStream_t stream) {
    const float* q = (const float*)d_in[0];
    const float* k = (const float*)d_in[1];
    const float* v = (const float*)d_in[2];
    // d_in[3] decay_mask (256MB) and d_in[4] intra_decay are recomputed on the fly
    float* out = (float*)d_out;

    unsigned short* kb = (unsigned short*)d_ws;                 // 16 MB
    unsigned short* vt = kb + (size_t)B_ * H_ * L_ * DK_;       // 16 MB

    int n4 = B_ * H_ * L_ * DK_ / 4;
    cvt_bf16_kernel<<<2048, 256, 0, stream>>>(k, kb, n4);
    transpose_v_kernel<<<B_ * H_ * (L_ / 64), 256, 0, stream>>>(v, vt);
    retention_kernel<<<B_ * H_ * NIT, 256, 0, stream>>>(q, kb, vt, out);
    fix_row0_kernel<<<B_ * H_, 64, 0, stream>>>(q, k, v, out);
}

// Round 6
// 89.286 us; speedup vs baseline: 1.4210x; 1.2482x over previous
//
#include <hip/hip_runtime.h>
#include <hip/hip_bf16.h>
#include <math.h>

// SelfRetentionV1: B=2,H=16,L=2048,DK=128,DV=128
// out[b,l,h,d] = RMSNorm_d( (QK^T * gamma^(i-j) / max(1,|rowsum|)) @ V )
#define B_ 2
#define H_ 16
#define L_ 2048
#define DK_ 128
#define DV_ 128
#define QBLK 64
#define KVBLK 64
#define NIT (L_/QBLK)   // 32

typedef __bf16 bf16x8 __attribute__((ext_vector_type(8)));
typedef float  f32x16 __attribute__((ext_vector_type(16)));

static __device__ __forceinline__ unsigned short f2bf(float f) {
    union { float f; unsigned int u; } x; x.f = f;
    unsigned int r = x.u + 0x7fffu + ((x.u >> 16) & 1u);  // RNE
    return (unsigned short)(r >> 16);
}

// async global->LDS, 16B per lane; LDS dest = wave-uniform base + lane*16
static __device__ __forceinline__ void gload_lds16(const void* g, void* l) {
    __builtin_amdgcn_global_load_lds(
        (const __attribute__((address_space(1))) unsigned int*)g,
        (__attribute__((address_space(3))) unsigned int*)l,
        16, 0, 0);
}

// K tile rows are 256B: swizzle bits 4-6 by row&7 (involution, row bits >=8)
#define KSWZ(d) ((d) ^ ((((d) >> 8) & 7) << 4))
// V tile rows are 128B: row bits >=7
#define VSWZ(d) ((d) ^ ((((d) >> 7) & 7) << 4))

// ---- pre-kernel 1: fp32 -> bf16 flat convert (K) ----
__global__ void cvt_bf16_kernel(const float* __restrict__ in,
                                unsigned short* __restrict__ out, int n4) {
    int i = blockIdx.x * blockDim.x + threadIdx.x;
    int stride = gridDim.x * blockDim.x;
    for (; i < n4; i += stride) {
        float4 f = ((const float4*)in)[i];
        uint2 o;
        o.x = (unsigned)f2bf(f.x) | ((unsigned)f2bf(f.y) << 16);
        o.y = (unsigned)f2bf(f.z) | ((unsigned)f2bf(f.w) << 16);
        ((uint2*)out)[i] = o;
    }
}

// ---- pre-kernel 2: V[bh][l][dv] -> VT[bh][dv][perm(l)], bf16 ----
// perm swaps bits 2<->3 of l so P-register order == mfma k-slot order in PV.
__global__ void transpose_v_kernel(const float* __restrict__ v,
                                   unsigned short* __restrict__ vt) {
    __shared__ unsigned short lds[64][130];   // +2 pad: col reads conflict-free
    int blk = blockIdx.x;
    int ltile = blk & (L_/64 - 1);
    int bh = blk / (L_/64);
    const float* vp = v + ((size_t)bh * L_ + (size_t)ltile * 64) * DV_;
    unsigned short* vo = vt + (size_t)bh * DV_ * L_ + ltile * 64;
    int t = threadIdx.x;
    int r0 = t >> 5, c0 = (t & 31) * 4;
    #pragma unroll
    for (int it = 0; it < 8; ++it) {
        int row = r0 + 8 * it;
        float4 f = *(const float4*)(vp + row * DV_ + c0);
        lds[row][c0 + 0] = f2bf(f.x);
        lds[row][c0 + 1] = f2bf(f.y);
        lds[row][c0 + 2] = f2bf(f.z);
        lds[row][c0 + 3] = f2bf(f.w);
    }
    __syncthreads();
    int dvb = t >> 3, seg = t & 7;
    #pragma unroll
    for (int ot = 0; ot < 4; ++ot) {
        int dv = dvb + 32 * ot;
        unsigned short a[8];
        #pragma unroll
        for (int tt = 0; tt < 8; ++tt) {
            int pp = seg * 8 + tt;
            int js = (pp & ~12) | ((pp & 4) << 1) | ((pp & 8) >> 1);  // swap b2,b3
            a[tt] = lds[js][dv];
        }
        uint4 st;
        st.x = (unsigned)a[0] | ((unsigned)a[1] << 16);
        st.y = (unsigned)a[2] | ((unsigned)a[3] << 16);
        st.z = (unsigned)a[4] | ((unsigned)a[5] << 16);
        st.w = (unsigned)a[6] | ((unsigned)a[7] << 16);
        *(uint4*)(vo + (size_t)dv * L_ + seg * 8) = st;
    }
}

// ---- main kernel: 4 waves (rh,kh); swapped QK^T keeps P in registers;
//      counted-vmcnt + raw s_barrier pipeline (no full drains mid-loop) ----
__launch_bounds__(256, 2)
__global__ void retention_kernel(const float* __restrict__ q,
                                 const unsigned short* __restrict__ kb,
                                 const unsigned short* __restrict__ vt_,
                                 float* __restrict__ out) {
    __shared__ __align__(16) unsigned short kbuf[2][64 * 128];  // 32 KB dbuf
    __shared__ __align__(16) unsigned short vbuf[2][128 * 64];  // 32 KB dbuf

    // bh->XCD-pinned remap (xcd = bid%8): 4 bh per XCD -> ~4MB K+V ~= L2
    int bid = blockIdx.x;
    int x    = bid & 7;
    int t_   = bid >> 3;
    int slot = t_ & 31;
    int hi   = t_ >> 5;
    int itile = (hi & 1) ? (31 - slot) : slot;
    int bh = hi * 8 + x;
    int b = bh >> 4, h = bh & 15;

    int tid = threadIdx.x;
    int lane = tid & 63;
    int w = tid >> 6;                   // 0..3
    int rh = w >> 1;                    // q-row half
    int kh = w & 1;                     // kv half
    int il = lane & 31;
    int hl = lane >> 5;

    int i_base = itile * QBLK + rh * 32;
    int i_row  = i_base + il;           // this lane's q-row

    const unsigned short* kbp = kb  + (size_t)bh * L_ * DK_;
    const unsigned short* vtp = vt_ + (size_t)bh * DV_ * L_;

    // ---- stage tile 0 (DMA runs under setup below) ----
    {
        const char* ksrc = (const char*)kbp;
        const char* vsrc = (const char*)vtp;
        char* kdst = (char*)&kbuf[0][0];
        char* vdst = (char*)&vbuf[0][0];
        #pragma unroll
        for (int is = 0; is < 4; ++is) {
            int dw = is * 4096 + w * 1024;
            int d  = dw + lane * 16;
            gload_lds16(ksrc + KSWZ(d), kdst + dw);
            int sv = VSWZ(d);
            gload_lds16(vsrc + (size_t)(sv >> 7) * (L_ * 2) + (sv & 127), vdst + dw);
        }
    }

    float ex = exp2f((float)(-5 - h));
    float gamma = 1.0f - ex;
    float log2g = log1pf(-ex) * 1.44269504088896f;

    // colfac[r] = gamma^(-jr), jr = (r&3) + 8*(r>>2) + 4*hl
    float gi  = exp2f(-log2g);
    float gi2 = gi * gi, gi3 = gi2 * gi, gi4 = gi2 * gi2;
    float gi8 = gi4 * gi4, gi16 = gi8 * gi8, gi24 = gi16 * gi8;
    float cfq[4] = {1.f, gi, gi2, gi3};
    float cfp[4] = {1.f, gi8, gi16, gi24};
    float chl = hl ? gi4 : 1.f;
    float colfac[16];
    #pragma unroll
    for (int r = 0; r < 16; ++r) colfac[r] = cfq[r & 3] * cfp[r >> 2] * chl;

    // arow = gamma^(i - jt*64 - kh*32), advanced by *= gamma^-64 per tile
    float arow = exp2f(log2g * (float)(i_row - kh * 32));
    float gm64i = exp2f(log2g * (-64.0f));
    int icmp = rh * 32 + il - kh * 32;   // diag mask: jr <= icmp

    // Q as B-operand: col = il (q-row i_row), k = ks*16 + hl*8 + 0..7
    bf16x8 qf[8];
    {
        const float* qp = q + ((size_t)bh * L_ + i_row) * DK_ + hl * 8;
        #pragma unroll
        for (int ks = 0; ks < 8; ++ks) {
            float4 f0 = *(const float4*)(qp + ks * 16);
            float4 f1 = *(const float4*)(qp + ks * 16 + 4);
            union { bf16x8 v; unsigned short u[8]; } A;
            A.u[0]=f2bf(f0.x); A.u[1]=f2bf(f0.y); A.u[2]=f2bf(f0.z); A.u[3]=f2bf(f0.w);
            A.u[4]=f2bf(f1.x); A.u[5]=f2bf(f1.y); A.u[6]=f2bf(f1.z); A.u[7]=f2bf(f1.w);
            qf[ks] = A.v;
        }
    }

    f32x16 o[4];                        // O^T: lane = dv (il), regs = i-pattern
    #pragma unroll
    for (int nt = 0; nt < 4; ++nt)
        #pragma unroll
        for (int e = 0; e < 16; ++e) o[nt][e] = 0.0f;
    float rowsum = 0.0f;                // per-lane: row i_row, this wave's j's

    int rswz = (il & 7) << 4;           // read-side XOR (rows == il mod 8)
    int krow256 = (kh * 32 + il) * 256;
    int hl16 = hl * 16;

    int cur = 0;
    for (int jt = 0; jt <= itile; ++jt) {
        // issue next stage, then wait for PREVIOUS stage only (counted vmcnt)
        if (jt < itile) {
            int jb = (jt + 1) * KVBLK;
            const char* ksrc = (const char*)(kbp + (size_t)jb * DK_);
            const char* vsrc = (const char*)(vtp + jb);
            char* kdst = (char*)&kbuf[cur ^ 1][0];
            char* vdst = (char*)&vbuf[cur ^ 1][0];
            #pragma unroll
            for (int is = 0; is < 4; ++is) {
                int dw = is * 4096 + w * 1024;
                int d  = dw + lane * 16;
                gload_lds16(ksrc + KSWZ(d), kdst + dw);
                int sv = VSWZ(d);
                gload_lds16(vsrc + (size_t)(sv >> 7) * (L_ * 2) + (sv & 127), vdst + dw);
            }
            asm volatile("s_waitcnt vmcnt(8)" ::: "memory");
        } else {
            asm volatile("s_waitcnt vmcnt(0)" ::: "memory");
        }
        asm volatile("s_barrier" ::: "memory");   // all waves' stage(jt) landed

        const char* kb_c = (const char*)&kbuf[cur][0];
        const char* vb_c = (const char*)&vbuf[cur][0];

        // ---- S^T = mfma(K, Q): lane = i, regs = j (swapped operands) ----
        f32x16 s;
        #pragma unroll
        for (int e = 0; e < 16; ++e) s[e] = 0.0f;
        #pragma unroll
        for (int ks = 0; ks < 8; ++ks) {
            bf16x8 kf = *(const bf16x8*)(kb_c + krow256 + ((ks * 32 + hl16) ^ rswz));
            s = __builtin_amdgcn_mfma_f32_32x32x16_bf16(kf, qf[ks], s, 0, 0, 0);
        }

        float ab = arow;
        arow *= gm64i;

        // ---- decay + (diag) mask + rowsum; P stays in registers ----
        float val[16];
        if (jt == itile) {
            #pragma unroll
            for (int r = 0; r < 16; ++r) {
                int jr = (r & 3) + 8 * (r >> 2) + 4 * hl;
                float vv = s[r] * (colfac[r] * ab);
                vv = (jr <= icmp) ? vv : 0.0f;
                rowsum += vv;
                val[r] = vv;
            }
        } else {
            #pragma unroll
            for (int r = 0; r < 16; ++r) {
                float vv = s[r] * (colfac[r] * ab);
                rowsum += vv;
                val[r] = vv;
            }
        }

        // ---- O^T += mfma(P, V_perm): pa[m] = val[8m..8m+7] (perm'd V rows) ----
        #pragma unroll
        for (int m = 0; m < 2; ++m) {
            union { bf16x8 v; unsigned short u[8]; } P_;
            #pragma unroll
            for (int e = 0; e < 8; ++e) P_.u[e] = f2bf(val[8 * m + e]);
            #pragma unroll
            for (int nt = 0; nt < 4; ++nt) {
                bf16x8 vb = *(const bf16x8*)(vb_c + (nt * 32 + il) * 128
                                             + ((kh * 64 + m * 32 + hl16) ^ rswz));
                o[nt] = __builtin_amdgcn_mfma_f32_32x32x16_bf16(P_.v, vb, o[nt], 0, 0, 0);
            }
        }

        asm volatile("s_barrier" ::: "memory");   // readers done before overwrite
        cur ^= 1;
    }

    // ---- rowsum: combine hl halves (each holds 16 of the wave's 32 j's) ----
    float rsw = rowsum + __shfl_xor(rowsum, 32);  // all lanes: wave-sum[row il]

    // ---- cross-kh reduction via LDS (buffers dead now) ----
    float* exch = (float*)&kbuf[0][0];
    float* rsx  = (float*)&vbuf[0][0];
    if (kh == 1) {
        float* eb = exch + rh * 4096;
        #pragma unroll
        for (int nt = 0; nt < 4; ++nt)
            #pragma unroll
            for (int qq = 0; qq < 4; ++qq) {
                float4 vv = { o[nt][4*qq+0], o[nt][4*qq+1],
                              o[nt][4*qq+2], o[nt][4*qq+3] };
                *(float4*)(eb + (nt * 4 + qq) * 256 + lane * 4) = vv;
            }
        if (lane < 32) rsx[rh * 32 + lane] = rsw;
    }
    __syncthreads();
    if (kh == 0) {
        float* eb = exch + rh * 4096;
        #pragma unroll
        for (int nt = 0; nt < 4; ++nt)
            #pragma unroll
            for (int qq = 0; qq < 4; ++qq) {
                float4 pv = *(const float4*)(eb + (nt * 4 + qq) * 256 + lane * 4);
                o[nt][4*qq+0] += pv.x; o[nt][4*qq+1] += pv.y;
                o[nt][4*qq+2] += pv.z; o[nt][4*qq+3] += pv.w;
            }
        float rtot = rsw + rsx[rh * 32 + il];
        float dnl = 1.0f / fmaxf(1.0f, fabsf(rtot));   // lane L&31 holds row L&31

        #pragma unroll
        for (int r = 0; r < 16; ++r) {
            int isrc = (r & 3) + 8 * (r >> 2) + 4 * hl;   // i_local of reg r
            float dn = __shfl(dnl, isrc);
            float ov[4];
            float ss = 0.0f;
            #pragma unroll
            for (int nt = 0; nt < 4; ++nt) { ov[nt] = o[nt][r] * dn; ss += ov[nt] * ov[nt]; }
            ss += __shfl_xor(ss, 1);
            ss += __shfl_xor(ss, 2);
            ss += __shfl_xor(ss, 4);
            ss += __shfl_xor(ss, 8);
            ss += __shfl_xor(ss, 16);
            float sc = rsqrtf(ss * (1.0f / 128.0f) + 1e-6f);
            int i_abs = i_base + isrc;
            float* op = out + (((size_t)b * L_ + i_abs) * H_ + h) * DV_ + il;
            #pragma unroll
            for (int nt = 0; nt < 4; ++nt) op[nt * 32] = ov[nt] * sc;
        }
    }
}

// ---- fp32 fixup for row i=0 (single-term row: eps-magnified bf16 error) ----
__global__ void fix_row0_kernel(const float* __restrict__ q,
                                const float* __restrict__ k,
                                const float* __restrict__ v,
                                float* __restrict__ out) {
    int bh = blockIdx.x;            // 0..31
    int lane = threadIdx.x;         // 0..63
    const float* qp = q + (size_t)bh * L_ * DK_;
    const float* kp = k + (size_t)bh * L_ * DK_;
    const float* vp = v + (size_t)bh * L_ * DV_;
    float part = qp[lane] * kp[lane] + qp[lane + 64] * kp[lane + 64];
    #pragma unroll
    for (int mm = 1; mm < 64; mm <<= 1) part += __shfl_xor(part, mm);
    float r00 = part;
    float cf = r00 / fmaxf(1.0f, fabsf(r00));
    float o0 = cf * vp[lane], o1 = cf * vp[lane + 64];
    float ss = o0 * o0 + o1 * o1;
    #pragma unroll
    for (int mm = 1; mm < 64; mm <<= 1) ss += __shfl_xor(ss, mm);
    float sc = rsqrtf(ss * (1.0f / 128.0f) + 1e-6f);
    int b = bh >> 4, h = bh & 15;
    float* op = out + ((size_t)b * L_ * H_ + h) * DV_;   // i = 0
    op[lane] = o0 * sc;
    op[lane + 64] = o1 * sc;
}

extern "C" void kernel_launch(void* const* d_in, const int* in_sizes, int n_in,
                              void* d_out, int out_size, void* d_ws, size_t ws_size,
                              hipStream_t stream) {
    const float* q = (const float*)d_in[0];
    const float* k = (const float*)d_in[1];
    const float* v = (const float*)d_in[2];
    // d_in[3] decay_mask (256MB) and d_in[4] intra_decay are recomputed on the fly
    float* out = (float*)d_out;

    unsigned short* kb = (unsigned short*)d_ws;                 // 16 MB
    unsigned short* vt = kb + (size_t)B_ * H_ * L_ * DK_;       // 16 MB

    int n4 = B_ * H_ * L_ * DK_ / 4;
    cvt_bf16_kernel<<<2048, 256, 0, stream>>>(k, kb, n4);
    transpose_v_kernel<<<B_ * H_ * (L_ / 64), 256, 0, stream>>>(v, vt);
    retention_kernel<<<B_ * H_ * NIT, 256, 0, stream>>>(q, kb, vt, out);
    fix_row0_kernel<<<B_ * H_, 64, 0, stream>>>(q, k, v, out);
}